// Round 2
// baseline (675.798 us; speedup 1.0000x reference)
//
#include <hip/hip_runtime.h>
#include <math.h>

#define L_TOT 4194304   // 2^22 upsampled samples
#define NFR   16384     // frames / f0 length
#define OUTN  4194048   // output length

// ---------- workspace layout (floats) ----------
// [0, L_TOT)                : cumsum tree levels 11..22 (packed; lower levels in LDS)
// [L_TOT, 2*L_TOT)          : pulse signal
// [2*L_TOT + 0,   +512)     : twiddle cos  (cos(2*pi*j/1024))
// [2*L_TOT + 512, +1024)    : twiddle sin
// [2*L_TOT + 1024,+2048)    : hann window (1024)
// [2*L_TOT + 2048,+2048+NFR): f0 = exp(log_f0)

__device__ __forceinline__ int lvl_off(int a) {
  return L_TOT - (L_TOT >> (a - 1));
}

// LDS bank swizzle for the 1024-entry float2 in-place FFT buffer.
// Folds ALL upper address bits into the low nibble so that every access
// pattern in this kernel (FFT strides 256/64/16/4/1, natural loops, and the
// digit-reversed gathers with entropy in bits 8/6) is conflict-free.
// Injectivity verified per 16-lane phase for each pattern; bijective on [0,1024).
__device__ __forceinline__ int swz(int e) {
  int h = (e >> 4) & 3, g = (e >> 6) & 3, f = (e >> 8) & 3;
  return e ^ (h * 5) ^ (g * 3) ^ ((f * 12) & 15);
}

// base-4 digit reversal of a 10-bit index (involution).
__device__ __forceinline__ int dr4(int p) {
  return ((p & 3) << 8) | (((p >> 2) & 3) << 6) | (((p >> 4) & 3) << 4) |
         (((p >> 6) & 3) << 2) | ((p >> 8) & 3);
}

// linear_interp(exp(log_f0), 256) at position j — matches reference rounding (no FMA)
__device__ __forceinline__ float f0_up_val(const float* f0arr, int j) {
  float pos = __fadd_rn(__fmul_rn(__fadd_rn((float)j, 0.5f), 1.0f / 256.0f), -0.5f);
  pos = fminf(fmaxf(pos, 0.0f), 16383.0f);
  int lo = (int)pos;
  int hi = min(lo + 1, NFR - 1);
  float frac = __fadd_rn(pos, -(float)lo);
  float a = __fmul_rn(f0arr[lo], __fadd_rn(1.0f, -frac));
  float b = __fmul_rn(f0arr[hi], frac);
  return __fadd_rn(a, b);
}

// full prefix sum replicating jax.lax.associative_scan bit-exactly (validated R4-R8).
__device__ float prefix_sum(const float* W, const float* f0arr, int m) {
  float acc = 0.0f;
  bool first = true;
  int pos = 0;
  for (int a = 22; a >= 1; --a) {
    if (m & (1 << a)) {
      float node = W[lvl_off(a) + (pos >> a)];
      acc = first ? node : __fadd_rn(acc, node);
      first = false;
      pos += (1 << a);
    }
  }
  if (m & 1) {
    float node = f0_up_val(f0arr, pos);
    acc = first ? node : __fadd_rn(acc, node);
  }
  return acc;
}

// ---------- init: twiddles, window, f0 ----------
__global__ __launch_bounds__(256) void init_tables(const float* __restrict__ logf0,
                                                   float* __restrict__ W) {
  int g = blockIdx.x * 256 + threadIdx.x;
  float* twc = W + 2 * L_TOT;
  float* tws = twc + 512;
  float* wh  = twc + 1024;
  float* f0arr = twc + 2048;
  if (g < 512) {
    double a = (double)g * 3.14159265358979323846 / 512.0; // 2*pi*g/1024
    twc[g] = (float)cos(a);
    tws[g] = (float)sin(a);
  }
  if (g < 1024) {
    double a = (double)g * 3.14159265358979323846 / 512.0;
    wh[g] = (float)(0.5 - 0.5 * cos(a));
  }
  if (g >= 2048 && g < 2048 + NFR) {
    f0arr[g - 2048] = (float)exp((double)logf0[g - 2048]);
  }
}

// ---------- cumsum tree: build levels 1..11, store only level 11 ----------
__global__ __launch_bounds__(256) void tree_kernel(float* W) {
  const float* f0arr = W + 2 * L_TOT + 2048;
  __shared__ float A[2048];
  __shared__ float B[1024];
  int tid = threadIdx.x;
  int base = blockIdx.x * 2048;
  for (int i = tid; i < 2048; i += 256) A[i] = f0_up_val(f0arr, base + i);
  __syncthreads();
  float* src = A;
  float* dst = B;
  int cnt = 1024;
  for (int a = 1; a <= 11; ++a) {
    int gbase = base >> a;
    for (int i = tid; i < cnt; i += 256) {
      float v = __fadd_rn(src[2 * i], src[2 * i + 1]);
      dst[i] = v;
      if (a == 11) W[lvl_off(11) + gbase + i] = v;
    }
    __syncthreads();
    float* tmp = src; src = dst; dst = tmp;
    cnt >>= 1;
  }
}

// ---------- cumsum tree, levels 12..22 ----------
__global__ __launch_bounds__(256) void tree_top_kernel(float* W) {
  __shared__ float A[2048];
  __shared__ float B[1024];
  int tid = threadIdx.x;
  for (int i = tid; i < 2048; i += 256) A[i] = W[lvl_off(11) + i];
  __syncthreads();
  float* src = A;
  float* dst = B;
  int cnt = 1024;
  for (int a = 12; a <= 22; ++a) {
    for (int i = tid; i < cnt; i += 256) {
      float v = __fadd_rn(src[2 * i], src[2 * i + 1]);
      dst[i] = v;
      W[lvl_off(a) + i] = v;
    }
    __syncthreads();
    float* tmp = src; src = dst; dst = tmp;
    cnt >>= 1;
  }
}

// ---------- impulse train v3 (bit-exact, validated R4-R8) ----------
__global__ __launch_bounds__(256) void pulse_kernel(float* W) {
  const float* f0arr = W + 2 * L_TOT + 2048;
  __shared__ float Tl[510];
  __shared__ float P[4100];
  int tid = threadIdx.x;
  int base = blockIdx.x * 4096;

  float v[16];
#pragma unroll
  for (int c = 0; c < 16; ++c) v[c] = f0_up_val(f0arr, base + 16 * tid + c);
  float s2[8], s4[4], s8[2];
#pragma unroll
  for (int j = 0; j < 8; ++j) s2[j] = __fadd_rn(v[2 * j], v[2 * j + 1]);
#pragma unroll
  for (int j = 0; j < 4; ++j) s4[j] = __fadd_rn(s2[2 * j], s2[2 * j + 1]);
  s8[0] = __fadd_rn(s4[0], s4[1]);
  s8[1] = __fadd_rn(s4[2], s4[3]);
  Tl[tid] = __fadd_rn(s8[0], s8[1]);
  __syncthreads();
  if (tid < 128) Tl[256 + tid] = __fadd_rn(Tl[2 * tid], Tl[2 * tid + 1]);
  __syncthreads();
  if (tid < 64)  Tl[384 + tid] = __fadd_rn(Tl[256 + 2 * tid], Tl[256 + 2 * tid + 1]);
  __syncthreads();
  if (tid < 32)  Tl[448 + tid] = __fadd_rn(Tl[384 + 2 * tid], Tl[384 + 2 * tid + 1]);
  __syncthreads();
  if (tid < 16)  Tl[480 + tid] = __fadd_rn(Tl[448 + 2 * tid], Tl[448 + 2 * tid + 1]);
  __syncthreads();
  if (tid < 8)   Tl[496 + tid] = __fadd_rn(Tl[480 + 2 * tid], Tl[480 + 2 * tid + 1]);
  __syncthreads();
  if (tid < 4)   Tl[504 + tid] = __fadd_rn(Tl[496 + 2 * tid], Tl[496 + 2 * tid + 1]);
  __syncthreads();
  if (tid < 2)   Tl[508 + tid] = __fadd_rn(Tl[504 + 2 * tid], Tl[504 + 2 * tid + 1]);
  __syncthreads();

  float accT = 0.0f;
  bool firstT = true;
  {
    int pos = 0;
    for (int a = 22; a >= 12; --a) {
      if (base & (1 << a)) {
        float node = W[lvl_off(a) + (pos >> a)];
        accT = firstT ? node : __fadd_rn(accT, node);
        firstT = false;
        pos += (1 << a);
      }
    }
  }
  float accM = accT;
  bool firstM = firstT;
  {
    int rh = 16 * tid;
    int lpos = 0;
    for (int a = 11; a >= 4; --a) {
      if (rh & (1 << a)) {
        float node = Tl[512 - (512 >> (a - 4)) + (lpos >> a)];
        accM = firstM ? node : __fadd_rn(accM, node);
        firstM = false;
        lpos += (1 << a);
      }
    }
  }
  if (tid >= 1) P[16 * tid] = accM;
#pragma unroll
  for (int c = 1; c <= 15; ++c) {
    float acc = accM;
    bool first = firstM;
    int lp = 0;
    if (c & 8) { float n = s8[lp >> 3]; acc = first ? n : __fadd_rn(acc, n); first = false; lp += 8; }
    if (c & 4) { float n = s4[lp >> 2]; acc = first ? n : __fadd_rn(acc, n); first = false; lp += 4; }
    if (c & 2) { float n = s2[lp >> 1]; acc = first ? n : __fadd_rn(acc, n); first = false; lp += 2; }
    if (c & 1) { float n = v[lp];       acc = first ? n : __fadd_rn(acc, n); }
    P[16 * tid + c] = acc;
  }
  if (tid == 0) P[4096] = prefix_sum(W, f0arr, base + 4096);
  if (tid == 1) {
    int m2 = base + 4097;
    P[4097] = (m2 <= L_TOT) ? prefix_sum(W, f0arr, m2) : 0.0f;
  }
  __syncthreads();

  float o[16];
#pragma unroll
  for (int c = 0; c < 16; ++c) {
    int i = base + 16 * tid + c;
    float P1 = P[16 * tid + c + 1];
    float P2 = (i == L_TOT - 1) ? prefix_sum(W, f0arr, 1)
                                : P[16 * tid + c + 2];
    float t1 = __fdiv_rn(P1, 24000.0f);
    float saw1 = __fadd_rn(t1, -floorf(t1));
    float t2 = __fdiv_rn(P2, 24000.0f);
    float saw2 = __fadd_rn(t2, -floorf(t2));
    float cc = __fdiv_rn(v[c], 24000.0f);
    o[c] = __fadd_rn(__fadd_rn(saw1, -saw2), cc);
  }
#pragma unroll
  for (int k = 0; k < 4; ++k)
    *(float4*)&W[L_TOT + base + 16 * tid + 4 * k] =
        make_float4(o[4 * k], o[4 * k + 1], o[4 * k + 2], o[4 * k + 3]);
}

// ---------- in-place radix-4 FFT, N=1024, 256 threads ----------
// DIF: natural input -> base-4 digit-reversed output.
// DIT: base-4 digit-reversed input -> natural output.
// Twiddles come from 4 per-thread REGISTER values twr[]:
//   twr[0]=w^tid, twr[1]=w^{4(tid&63)}, twr[2]=w^{16(tid&15)}, twr[3]=w^{64(tid&3)}
// (the exponent sets of all DIF and DIT stages coincide). w = e^{+2pi i/1024};
// DIR<0 conjugates. Each thread RMWs its own 4 elements -> in-place safe.
template <int DIR>
__device__ __forceinline__ void fft_dif(float2* F, const float2 (&twr)[4]) {
  int tid = threadIdx.x;
  __syncthreads();
#pragma unroll
  for (int s = 0; s < 5; ++s) {
    int L = 256 >> (2 * s);
    int q = tid & (L - 1);
    int base = ((tid >> (8 - 2 * s)) << (10 - 2 * s)) | q;
    float ur, ui;
    if (s < 4) { ur = twr[s].x; ui = twr[s].y; } else { ur = 1.0f; ui = 0.0f; }
    if (DIR < 0) ui = -ui;
    int e0 = swz(base), e1 = swz(base + L), e2 = swz(base + 2 * L), e3 = swz(base + 3 * L);
    float2 x0 = F[e0], x1 = F[e1], x2 = F[e2], x3 = F[e3];
    float s0r = x0.x + x2.x, s0i = x0.y + x2.y;
    float s1r = x1.x + x3.x, s1i = x1.y + x3.y;
    float d0r = x0.x - x2.x, d0i = x0.y - x2.y;
    float ddr = x1.x - x3.x, ddi = x1.y - x3.y;
    float t3r = (DIR > 0) ? -ddi : ddi;      // DIR*i*(x1-x3)
    float t3i = (DIR > 0) ? ddr : -ddr;
    float vr = ur * ur - ui * ui, vi = 2.0f * ur * ui;      // w^{2q'}
    float w3r = ur * vr - ui * vi, w3i = ur * vi + ui * vr; // w^{3q'}
    F[e0] = make_float2(s0r + s1r, s0i + s1i);
    float a1r = d0r + t3r, a1i = d0i + t3i;
    F[e1] = make_float2(a1r * ur - a1i * ui, a1r * ui + a1i * ur);
    float a2r = s0r - s1r, a2i = s0i - s1i;
    F[e2] = make_float2(a2r * vr - a2i * vi, a2r * vi + a2i * vr);
    float a3r = d0r - t3r, a3i = d0i - t3i;
    F[e3] = make_float2(a3r * w3r - a3i * w3i, a3r * w3i + a3i * w3r);
    __syncthreads();
  }
}

template <int DIR>
__device__ __forceinline__ void fft_dit(float2* F, const float2 (&twr)[4]) {
  int tid = threadIdx.x;
  __syncthreads();
#pragma unroll
  for (int s = 0; s < 5; ++s) {
    int L = 1 << (2 * s);
    int q = tid & (L - 1);
    int base = ((tid >> (2 * s)) << (2 * s + 2)) | q;
    float ur, ui;
    if (s > 0) { ur = twr[4 - s].x; ui = twr[4 - s].y; } else { ur = 1.0f; ui = 0.0f; }
    if (DIR < 0) ui = -ui;
    int e0 = swz(base), e1 = swz(base + L), e2 = swz(base + 2 * L), e3 = swz(base + 3 * L);
    float2 x0 = F[e0], x1 = F[e1], x2 = F[e2], x3 = F[e3];
    float vr = ur * ur - ui * ui, vi = 2.0f * ur * ui;
    float w3r = ur * vr - ui * vi, w3i = ur * vi + ui * vr;
    float b1r = x1.x * ur - x1.y * ui, b1i = x1.x * ui + x1.y * ur;
    float b2r = x2.x * vr - x2.y * vi, b2i = x2.x * vi + x2.y * vr;
    float b3r = x3.x * w3r - x3.y * w3i, b3i = x3.x * w3i + x3.y * w3r;
    float s0r = x0.x + b2r, s0i = x0.y + b2i;
    float d0r = x0.x - b2r, d0i = x0.y - b2i;
    float s1r = b1r + b3r, s1i = b1i + b3i;
    float ddr = b1r - b3r, ddi = b1i - b3i;
    float d1r = (DIR > 0) ? -ddi : ddi;      // DIR*i*(t1-t3)
    float d1i = (DIR > 0) ? ddr : -ddr;
    F[e0] = make_float2(s0r + s1r, s0i + s1i);
    F[e1] = make_float2(d0r + d1r, d0i + d1i);
    F[e2] = make_float2(s0r - s1r, s0i - s1i);
    F[e3] = make_float2(d0r - d1r, d0i - d1i);
    __syncthreads();
  }
}

// spectral combine for one bin k (F holds a DIF output, i.e. dr order):
// H[k] <- Sp[k]*H[k] + Sn[k]*An
__device__ __forceinline__ void combine_one(int k, float An, const float2* F, float2* H) {
  int k2 = (1024 - k) & 1023;
  float2 z = F[swz(dr4(k))], mm = F[swz(dr4(k2))];
  float Ar = 0.5f * (z.x + mm.x), Ai = 0.5f * (z.y - mm.y);  // even (noise) part
  float Br = 0.5f * (z.y + mm.y), Bi = 0.5f * (mm.x - z.x);  // odd (pulse) part
  float2 h = H[k];
  H[k] = make_float2(Br * h.x - Bi * h.y + Ar * An,
                     Br * h.y + Bi * h.x + Ai * An);
}

// ---------- per-block fused kernel: TWO adjacent frames, 5 in-place FFTs ----------
// LDS = F[1024] + hA/hB[513] = 16400 B -> 8 blocks/CU (wave-cap 32/CU reached).
// Twiddles + hann weights hoisted to registers. launch_bounds(256,8) pins VGPR<=64.
__global__ __launch_bounds__(256, 8) void column_kernel(
    const float* __restrict__ noise,
    const float* __restrict__ envn,
    const float* __restrict__ envp,
    const float* __restrict__ W,
    float* __restrict__ out) {
  __shared__ float2 F[1024];             // single in-place FFT buffer
  __shared__ float2 hA[513], hB[513];
  int tid = threadIdx.x;
  int bid = blockIdx.x;
  // XCD swizzle: each XCD streams a contiguous frame range (env L2 locality).
  int g = (bid & 7) * 1024 + (bid >> 3);
  int fA = 2 * g;                        // frames fA, fA+1
  const float* pulse = W + L_TOT;
  const float* gtab = W + 2 * L_TOT;
  const float* whg = gtab + 1024;

  // per-thread register tables: twiddles (see fft header) and hann weights
  float2 twr[4];
  {
    int x1 = (tid & 63) << 2, x2 = (tid & 15) << 4, x3 = (tid & 3) << 6;
    twr[0] = make_float2(gtab[tid], gtab[512 + tid]);
    twr[1] = make_float2(gtab[x1], gtab[512 + x1]);
    twr[2] = make_float2(gtab[x2], gtab[512 + x2]);
    twr[3] = make_float2(gtab[x3], gtab[512 + x3]);
  }
  float wvr[4];
#pragma unroll
  for (int k = 0; k < 4; ++k) wvr[k] = whg[tid + 256 * k];

  for (int k = tid; k < 513; k += 256) {
    float2 e = *(const float2*)&envp[k * NFR + fA];   // fA even -> 8B aligned
    hA[k] = e;                                        // (log ampA, log ampB)
  }
  __syncthreads();

  // ---- (1) packed cepstrum: z = envA_sym + i*envB_sym (both real even) ----
#pragma unroll
  for (int j = 0; j < 4; ++j) {
    int i = tid + 256 * j;
    int k = (i <= 512) ? i : 1024 - i;
    F[swz(i)] = hA[k];
  }
  fft_dif<+1>(F, twr);                   // output in dr order
  // cep fold at k=dr4(p): scales 2^-10 / 2^-9 exact; upper half -> 0
#pragma unroll
  for (int j = 0; j < 4; ++j) {
    int p = tid + 256 * j;
    int k = dr4(p);
    float sc = ((k & 511) == 0) ? (1.0f / 1024.0f)
                                : ((k < 512) ? (2.0f / 1024.0f) : 0.0f);
    int e = swz(p);
    float2 a = F[e];
    F[e] = make_float2(a.x * sc, a.y * sc);
  }
  // ---- (2) packed rfft of two real cepstra; hermitian unpack; H=exp ----
  fft_dit<-1>(F, twr);                   // dr input -> natural output
  for (int k = tid; k < 513; k += 256) {
    int k2 = (1024 - k) & 1023;
    float2 z = F[swz(k)], mm = F[swz(k2)];
    float GAr = 0.5f * (z.x + mm.x), GAi = 0.5f * (z.y - mm.y);
    float GBr = 0.5f * (z.y + mm.y), GBi = 0.5f * (mm.x - z.x);
    float er = expf(GAr);
    float si, co;
    sincosf(GAi, &si, &co);
    hA[k] = make_float2(er * co, er * si);
    er = expf(GBr);
    sincosf(GBi, &si, &co);
    hB[k] = make_float2(er * co, er * si);
  }
  __syncthreads();   // F reads above must finish before (3) overwrites F

  // ---- (3) frame A: pack z = noise + i*pulse (windowed, reflect-padded) ----
#pragma unroll
  for (int j = 0; j < 4; ++j) {
    int i = tid + 256 * j;
    int q = 256 * fA - 256 + i;
    if (q < 0) q = -q;
    else if (q >= L_TOT) q = 2 * L_TOT - 2 - q;
    float wv = wvr[j];
    F[swz(i)] = make_float2(noise[q] * wv, pulse[q] * wv);
  }
  fft_dif<-1>(F, twr);                   // dr-order spectrum
  float2 eA0 = *(const float2*)&envn[tid * NFR + fA];
  combine_one(tid, expf(eA0.x), F, hA);
  float2 eA1 = *(const float2*)&envn[(tid + 256) * NFR + fA];
  combine_one(tid + 256, expf(eA1.x), F, hA);
  float2 eA2 = make_float2(0.0f, 0.0f);
  if (tid == 0) {
    eA2 = *(const float2*)&envn[512 * NFR + fA];
    combine_one(512, expf(eA2.x), F, hA);
  }
  __syncthreads();   // F gathers above must finish before (4) overwrites F

  // ---- (4) frame B ----
#pragma unroll
  for (int j = 0; j < 4; ++j) {
    int i = tid + 256 * j;
    int q = 256 * fA + i;                // frame fA+1 start - 256 (q >= 0)
    if (q >= L_TOT) q = 2 * L_TOT - 2 - q;
    float wv = wvr[j];
    F[swz(i)] = make_float2(noise[q] * wv, pulse[q] * wv);
  }
  fft_dif<-1>(F, twr);
  combine_one(tid, expf(eA0.y), F, hB);
  combine_one(tid + 256, expf(eA1.y), F, hB);
  if (tid == 0) combine_one(512, expf(eA2.y), F, hB);
  __syncthreads();   // hA/hB visibility + F gathers done before (5) writes

  // ---- (5) packed hermitian inverse: Z = YA_full + i*YB_full, at dr positions ----
#pragma unroll
  for (int j = 0; j < 4; ++j) {
    int i = tid + 256 * j;
    float2 zv;
    if (i <= 512) {
      zv = make_float2(hA[i].x - hB[i].y, hA[i].y + hB[i].x);
    } else {
      int jj = 1024 - i;
      zv = make_float2(hA[jj].x + hB[jj].y, hB[jj].x - hA[jj].y);
    }
    F[swz(dr4(i))] = zv;
  }
  fft_dit<+1>(F, twr);                   // natural-order time signal
  // fused OLA over the combined 1280-sample span: ya(i) + yb(i-256)
  const float scl = 1.0f / 1536.0f;      // 1/1024 FFT scale * 1/1.5 wsq
#pragma unroll
  for (int j = 0; j < 5; ++j) {
    int i = tid + 256 * j;
    float val = 0.0f;
    if (j < 4) val = F[swz(i)].x * (wvr[j] * scl);
    if (j > 0) val += F[swz(i - 256)].y * (wvr[j - 1] * scl);
    int t = 256 * fA - 512 + i;
    if (t >= 0 && t < OUTN) atomicAdd(&out[t], val);
  }
}

// ---------- edge fix-up: first/last 256 samples have <4 window terms ----------
__global__ __launch_bounds__(256) void finalize_kernel(float* __restrict__ out,
                                                       const float* __restrict__ W) {
  const float* wh = W + 2 * L_TOT + 1024;
  int tid = threadIdx.x;
  int t = (blockIdx.x == 0) ? tid : (OUTN - 256 + tid);
  int p = t + 512;
  int jmin = max(0, (p - 768) >> 8);
  int jmax = min(NFR - 1, p >> 8);
  float wsq = 0.0f;
  for (int j = jmin; j <= jmax; ++j) {
    float w = wh[p - 256 * j];
    wsq += w * w;
  }
  out[t] = out[t] * (1.5f / fmaxf(wsq, 1e-11f));
}

extern "C" void kernel_launch(void* const* d_in, const int* in_sizes, int n_in,
                              void* d_out, int out_size, void* d_ws, size_t ws_size,
                              hipStream_t stream) {
  const float* logf0 = (const float*)d_in[0];
  const float* envn  = (const float*)d_in[1];
  const float* envp  = (const float*)d_in[2];
  const float* noise = (const float*)d_in[3];
  float* out = (float*)d_out;
  float* W = (float*)d_ws;

  init_tables<<<dim3(72), dim3(256), 0, stream>>>(logf0, W);
  tree_kernel<<<dim3(2048), dim3(256), 0, stream>>>(W);
  tree_top_kernel<<<dim3(1), dim3(256), 0, stream>>>(W);
  pulse_kernel<<<dim3(L_TOT / 4096), dim3(256), 0, stream>>>(W);
  hipMemsetAsync(d_out, 0, (size_t)out_size * sizeof(float), stream);
  column_kernel<<<dim3(NFR / 2), dim3(256), 0, stream>>>(noise, envn, envp, W, out);
  finalize_kernel<<<dim3(2), dim3(256), 0, stream>>>(out, W);
}

// Round 3
// 277.671 us; speedup vs baseline: 2.4338x; 2.4338x over previous
//
#include <hip/hip_runtime.h>
#include <math.h>

#define L_TOT 4194304   // 2^22 upsampled samples
#define NFR   16384     // frames / f0 length
#define OUTN  4194048   // output length

// ---------- workspace layout (floats) ----------
// [0, L_TOT)                : cumsum tree levels 11..22 (packed; lower levels in LDS)
// [L_TOT, 2*L_TOT)          : pulse signal
// [2*L_TOT + 0,   +512)     : twiddle cos  (cos(2*pi*j/1024))
// [2*L_TOT + 512, +1024)    : twiddle sin
// [2*L_TOT + 1024,+2048)    : hann window (1024)
// [2*L_TOT + 2048,+2048+NFR): f0 = exp(log_f0)

__device__ __forceinline__ int lvl_off(int a) {
  return L_TOT - (L_TOT >> (a - 1));
}

// LDS bank swizzle for the 1024-entry float2 in-place FFT buffer.
// Folds ALL upper address bits into the low nibble so that every access
// pattern in this kernel (FFT strides 256/64/16/4/1, natural loops, and the
// digit-reversed gathers with entropy in bits 8/6) is conflict-free.
__device__ __forceinline__ int swz(int e) {
  int h = (e >> 4) & 3, g = (e >> 6) & 3, f = (e >> 8) & 3;
  return e ^ (h * 5) ^ (g * 3) ^ ((f * 12) & 15);
}

// base-4 digit reversal of a 10-bit index (involution).
__device__ __forceinline__ int dr4(int p) {
  return ((p & 3) << 8) | (((p >> 2) & 3) << 6) | (((p >> 4) & 3) << 4) |
         (((p >> 6) & 3) << 2) | ((p >> 8) & 3);
}

// linear_interp(exp(log_f0), 256) at position j — matches reference rounding (no FMA)
__device__ __forceinline__ float f0_up_val(const float* f0arr, int j) {
  float pos = __fadd_rn(__fmul_rn(__fadd_rn((float)j, 0.5f), 1.0f / 256.0f), -0.5f);
  pos = fminf(fmaxf(pos, 0.0f), 16383.0f);
  int lo = (int)pos;
  int hi = min(lo + 1, NFR - 1);
  float frac = __fadd_rn(pos, -(float)lo);
  float a = __fmul_rn(f0arr[lo], __fadd_rn(1.0f, -frac));
  float b = __fmul_rn(f0arr[hi], frac);
  return __fadd_rn(a, b);
}

// full prefix sum replicating jax.lax.associative_scan bit-exactly (validated R4-R8).
__device__ float prefix_sum(const float* W, const float* f0arr, int m) {
  float acc = 0.0f;
  bool first = true;
  int pos = 0;
  for (int a = 22; a >= 1; --a) {
    if (m & (1 << a)) {
      float node = W[lvl_off(a) + (pos >> a)];
      acc = first ? node : __fadd_rn(acc, node);
      first = false;
      pos += (1 << a);
    }
  }
  if (m & 1) {
    float node = f0_up_val(f0arr, pos);
    acc = first ? node : __fadd_rn(acc, node);
  }
  return acc;
}

// ---------- init: twiddles, window, f0 ----------
__global__ __launch_bounds__(256) void init_tables(const float* __restrict__ logf0,
                                                   float* __restrict__ W) {
  int g = blockIdx.x * 256 + threadIdx.x;
  float* twc = W + 2 * L_TOT;
  float* tws = twc + 512;
  float* wh  = twc + 1024;
  float* f0arr = twc + 2048;
  if (g < 512) {
    double a = (double)g * 3.14159265358979323846 / 512.0; // 2*pi*g/1024
    twc[g] = (float)cos(a);
    tws[g] = (float)sin(a);
  }
  if (g < 1024) {
    double a = (double)g * 3.14159265358979323846 / 512.0;
    wh[g] = (float)(0.5 - 0.5 * cos(a));
  }
  if (g >= 2048 && g < 2048 + NFR) {
    f0arr[g - 2048] = (float)exp((double)logf0[g - 2048]);
  }
}

// ---------- cumsum tree: build levels 1..11, store only level 11 ----------
__global__ __launch_bounds__(256) void tree_kernel(float* W) {
  const float* f0arr = W + 2 * L_TOT + 2048;
  __shared__ float A[2048];
  __shared__ float B[1024];
  int tid = threadIdx.x;
  int base = blockIdx.x * 2048;
  for (int i = tid; i < 2048; i += 256) A[i] = f0_up_val(f0arr, base + i);
  __syncthreads();
  float* src = A;
  float* dst = B;
  int cnt = 1024;
  for (int a = 1; a <= 11; ++a) {
    int gbase = base >> a;
    for (int i = tid; i < cnt; i += 256) {
      float v = __fadd_rn(src[2 * i], src[2 * i + 1]);
      dst[i] = v;
      if (a == 11) W[lvl_off(11) + gbase + i] = v;
    }
    __syncthreads();
    float* tmp = src; src = dst; dst = tmp;
    cnt >>= 1;
  }
}

// ---------- cumsum tree, levels 12..22 ----------
__global__ __launch_bounds__(256) void tree_top_kernel(float* W) {
  __shared__ float A[2048];
  __shared__ float B[1024];
  int tid = threadIdx.x;
  for (int i = tid; i < 2048; i += 256) A[i] = W[lvl_off(11) + i];
  __syncthreads();
  float* src = A;
  float* dst = B;
  int cnt = 1024;
  for (int a = 12; a <= 22; ++a) {
    for (int i = tid; i < cnt; i += 256) {
      float v = __fadd_rn(src[2 * i], src[2 * i + 1]);
      dst[i] = v;
      W[lvl_off(a) + i] = v;
    }
    __syncthreads();
    float* tmp = src; src = dst; dst = tmp;
    cnt >>= 1;
  }
}

// ---------- impulse train v3 (bit-exact, validated R4-R8) ----------
__global__ __launch_bounds__(256) void pulse_kernel(float* W) {
  const float* f0arr = W + 2 * L_TOT + 2048;
  __shared__ float Tl[510];
  __shared__ float P[4100];
  int tid = threadIdx.x;
  int base = blockIdx.x * 4096;

  float v[16];
#pragma unroll
  for (int c = 0; c < 16; ++c) v[c] = f0_up_val(f0arr, base + 16 * tid + c);
  float s2[8], s4[4], s8[2];
#pragma unroll
  for (int j = 0; j < 8; ++j) s2[j] = __fadd_rn(v[2 * j], v[2 * j + 1]);
#pragma unroll
  for (int j = 0; j < 4; ++j) s4[j] = __fadd_rn(s2[2 * j], s2[2 * j + 1]);
  s8[0] = __fadd_rn(s4[0], s4[1]);
  s8[1] = __fadd_rn(s4[2], s4[3]);
  Tl[tid] = __fadd_rn(s8[0], s8[1]);
  __syncthreads();
  if (tid < 128) Tl[256 + tid] = __fadd_rn(Tl[2 * tid], Tl[2 * tid + 1]);
  __syncthreads();
  if (tid < 64)  Tl[384 + tid] = __fadd_rn(Tl[256 + 2 * tid], Tl[256 + 2 * tid + 1]);
  __syncthreads();
  if (tid < 32)  Tl[448 + tid] = __fadd_rn(Tl[384 + 2 * tid], Tl[384 + 2 * tid + 1]);
  __syncthreads();
  if (tid < 16)  Tl[480 + tid] = __fadd_rn(Tl[448 + 2 * tid], Tl[448 + 2 * tid + 1]);
  __syncthreads();
  if (tid < 8)   Tl[496 + tid] = __fadd_rn(Tl[480 + 2 * tid], Tl[480 + 2 * tid + 1]);
  __syncthreads();
  if (tid < 4)   Tl[504 + tid] = __fadd_rn(Tl[496 + 2 * tid], Tl[496 + 2 * tid + 1]);
  __syncthreads();
  if (tid < 2)   Tl[508 + tid] = __fadd_rn(Tl[504 + 2 * tid], Tl[504 + 2 * tid + 1]);
  __syncthreads();

  float accT = 0.0f;
  bool firstT = true;
  {
    int pos = 0;
    for (int a = 22; a >= 12; --a) {
      if (base & (1 << a)) {
        float node = W[lvl_off(a) + (pos >> a)];
        accT = firstT ? node : __fadd_rn(accT, node);
        firstT = false;
        pos += (1 << a);
      }
    }
  }
  float accM = accT;
  bool firstM = firstT;
  {
    int rh = 16 * tid;
    int lpos = 0;
    for (int a = 11; a >= 4; --a) {
      if (rh & (1 << a)) {
        float node = Tl[512 - (512 >> (a - 4)) + (lpos >> a)];
        accM = firstM ? node : __fadd_rn(accM, node);
        firstM = false;
        lpos += (1 << a);
      }
    }
  }
  if (tid >= 1) P[16 * tid] = accM;
#pragma unroll
  for (int c = 1; c <= 15; ++c) {
    float acc = accM;
    bool first = firstM;
    int lp = 0;
    if (c & 8) { float n = s8[lp >> 3]; acc = first ? n : __fadd_rn(acc, n); first = false; lp += 8; }
    if (c & 4) { float n = s4[lp >> 2]; acc = first ? n : __fadd_rn(acc, n); first = false; lp += 4; }
    if (c & 2) { float n = s2[lp >> 1]; acc = first ? n : __fadd_rn(acc, n); first = false; lp += 2; }
    if (c & 1) { float n = v[lp];       acc = first ? n : __fadd_rn(acc, n); }
    P[16 * tid + c] = acc;
  }
  if (tid == 0) P[4096] = prefix_sum(W, f0arr, base + 4096);
  if (tid == 1) {
    int m2 = base + 4097;
    P[4097] = (m2 <= L_TOT) ? prefix_sum(W, f0arr, m2) : 0.0f;
  }
  __syncthreads();

  float o[16];
#pragma unroll
  for (int c = 0; c < 16; ++c) {
    int i = base + 16 * tid + c;
    float P1 = P[16 * tid + c + 1];
    float P2 = (i == L_TOT - 1) ? prefix_sum(W, f0arr, 1)
                                : P[16 * tid + c + 2];
    float t1 = __fdiv_rn(P1, 24000.0f);
    float saw1 = __fadd_rn(t1, -floorf(t1));
    float t2 = __fdiv_rn(P2, 24000.0f);
    float saw2 = __fadd_rn(t2, -floorf(t2));
    float cc = __fdiv_rn(v[c], 24000.0f);
    o[c] = __fadd_rn(__fadd_rn(saw1, -saw2), cc);
  }
#pragma unroll
  for (int k = 0; k < 4; ++k)
    *(float4*)&W[L_TOT + base + 16 * tid + 4 * k] =
        make_float4(o[4 * k], o[4 * k + 1], o[4 * k + 2], o[4 * k + 3]);
}

// ---------- in-place radix-4 FFT, N=1024, 256 threads ----------
// DIF: natural -> base-4 digit-reversed.  DIT: digit-reversed -> natural.
// Twiddles are NAMED register scalars (tw0..tw3), passed by value — no indexed
// arrays anywhere (R2 lesson: indexed per-thread arrays + tight launch_bounds
// demoted them to scratch -> 2 GB/dispatch of spill traffic).
//   tw0=w^tid, tw1=w^{4(tid&63)}, tw2=w^{16(tid&15)}, tw3=w^{64(tid&3)}
// w = e^{+2pi i/1024}; DIR<0 conjugates. Each thread RMWs its own 4 elements.

template <int DIR>
__device__ __forceinline__ void bfly_dif(float2* F, int base, int L, float ur, float ui) {
  if (DIR < 0) ui = -ui;
  int e0 = swz(base), e1 = swz(base + L), e2 = swz(base + 2 * L), e3 = swz(base + 3 * L);
  float2 x0 = F[e0], x1 = F[e1], x2 = F[e2], x3 = F[e3];
  float s0r = x0.x + x2.x, s0i = x0.y + x2.y;
  float s1r = x1.x + x3.x, s1i = x1.y + x3.y;
  float d0r = x0.x - x2.x, d0i = x0.y - x2.y;
  float ddr = x1.x - x3.x, ddi = x1.y - x3.y;
  float t3r = (DIR > 0) ? -ddi : ddi;      // DIR*i*(x1-x3)
  float t3i = (DIR > 0) ? ddr : -ddr;
  float vr = ur * ur - ui * ui, vi = 2.0f * ur * ui;      // w^{2q'}
  float w3r = ur * vr - ui * vi, w3i = ur * vi + ui * vr; // w^{3q'}
  F[e0] = make_float2(s0r + s1r, s0i + s1i);
  float a1r = d0r + t3r, a1i = d0i + t3i;
  F[e1] = make_float2(a1r * ur - a1i * ui, a1r * ui + a1i * ur);
  float a2r = s0r - s1r, a2i = s0i - s1i;
  F[e2] = make_float2(a2r * vr - a2i * vi, a2r * vi + a2i * vr);
  float a3r = d0r - t3r, a3i = d0i - t3i;
  F[e3] = make_float2(a3r * w3r - a3i * w3i, a3r * w3i + a3i * w3r);
  __syncthreads();
}

template <int DIR>
__device__ __forceinline__ void bfly_dit(float2* F, int base, int L, float ur, float ui) {
  if (DIR < 0) ui = -ui;
  int e0 = swz(base), e1 = swz(base + L), e2 = swz(base + 2 * L), e3 = swz(base + 3 * L);
  float2 x0 = F[e0], x1 = F[e1], x2 = F[e2], x3 = F[e3];
  float vr = ur * ur - ui * ui, vi = 2.0f * ur * ui;
  float w3r = ur * vr - ui * vi, w3i = ur * vi + ui * vr;
  float b1r = x1.x * ur - x1.y * ui, b1i = x1.x * ui + x1.y * ur;
  float b2r = x2.x * vr - x2.y * vi, b2i = x2.x * vi + x2.y * vr;
  float b3r = x3.x * w3r - x3.y * w3i, b3i = x3.x * w3i + x3.y * w3r;
  float s0r = x0.x + b2r, s0i = x0.y + b2i;
  float d0r = x0.x - b2r, d0i = x0.y - b2i;
  float s1r = b1r + b3r, s1i = b1i + b3i;
  float ddr = b1r - b3r, ddi = b1i - b3i;
  float d1r = (DIR > 0) ? -ddi : ddi;      // DIR*i*(t1-t3)
  float d1i = (DIR > 0) ? ddr : -ddr;
  F[e0] = make_float2(s0r + s1r, s0i + s1i);
  F[e1] = make_float2(d0r + d1r, d0i + d1i);
  F[e2] = make_float2(s0r - s1r, s0i - s1i);
  F[e3] = make_float2(d0r - d1r, d0i - d1i);
  __syncthreads();
}

template <int DIR>
__device__ __forceinline__ void fft_dif(float2* F, int tid, float2 t0, float2 t1,
                                        float2 t2, float2 t3) {
  __syncthreads();
  // s=0: L=256
  bfly_dif<DIR>(F, tid, 256, t0.x, t0.y);
  // s=1: L=64
  bfly_dif<DIR>(F, ((tid >> 6) << 8) | (tid & 63), 64, t1.x, t1.y);
  // s=2: L=16
  bfly_dif<DIR>(F, ((tid >> 4) << 6) | (tid & 15), 16, t2.x, t2.y);
  // s=3: L=4
  bfly_dif<DIR>(F, ((tid >> 2) << 4) | (tid & 3), 4, t3.x, t3.y);
  // s=4: L=1
  bfly_dif<DIR>(F, tid << 2, 1, 1.0f, 0.0f);
}

template <int DIR>
__device__ __forceinline__ void fft_dit(float2* F, int tid, float2 t0, float2 t1,
                                        float2 t2, float2 t3) {
  __syncthreads();
  // s=0: L=1
  bfly_dit<DIR>(F, tid << 2, 1, 1.0f, 0.0f);
  // s=1: L=4
  bfly_dit<DIR>(F, ((tid >> 2) << 4) | (tid & 3), 4, t3.x, t3.y);
  // s=2: L=16
  bfly_dit<DIR>(F, ((tid >> 4) << 6) | (tid & 15), 16, t2.x, t2.y);
  // s=3: L=64
  bfly_dit<DIR>(F, ((tid >> 6) << 8) | (tid & 63), 64, t1.x, t1.y);
  // s=4: L=256
  bfly_dit<DIR>(F, tid, 256, t0.x, t0.y);
}

// spectral combine for one bin k (F holds a DIF output, i.e. dr order):
// H[k] <- Sp[k]*H[k] + Sn[k]*An
__device__ __forceinline__ void combine_one(int k, float An, const float2* F, float2* H) {
  int k2 = (1024 - k) & 1023;
  float2 z = F[swz(dr4(k))], mm = F[swz(dr4(k2))];
  float Ar = 0.5f * (z.x + mm.x), Ai = 0.5f * (z.y - mm.y);  // even (noise) part
  float Br = 0.5f * (z.y + mm.y), Bi = 0.5f * (mm.x - z.x);  // odd (pulse) part
  float2 h = H[k];
  H[k] = make_float2(Br * h.x - Bi * h.y + Ar * An,
                     Br * h.y + Bi * h.x + Ai * An);
}

// ---------- per-block fused kernel: TWO adjacent frames, 5 in-place FFTs ----------
// LDS = F[1024] + hA/hB[513] = 16400 B -> 8 blocks/CU (wave cap). No launch_bounds
// min-wave clamp (R2 regression); all per-thread state is named scalars.
__global__ __launch_bounds__(256) void column_kernel(
    const float* __restrict__ noise,
    const float* __restrict__ envn,
    const float* __restrict__ envp,
    const float* __restrict__ W,
    float* __restrict__ out) {
  __shared__ float2 F[1024];             // single in-place FFT buffer
  __shared__ float2 hA[513], hB[513];
  int tid = threadIdx.x;
  int bid = blockIdx.x;
  // XCD swizzle: each XCD streams a contiguous frame range (env L2 locality).
  int g = (bid & 7) * 1024 + (bid >> 3);
  int fA = 2 * g;                        // frames fA, fA+1
  const float* pulse = W + L_TOT;
  const float* gtab = W + 2 * L_TOT;
  const float* whg = gtab + 1024;

  // per-thread register twiddles (named scalars; see fft header)
  int x1 = (tid & 63) << 2, x2 = (tid & 15) << 4, x3 = (tid & 3) << 6;
  float2 tw0 = make_float2(gtab[tid], gtab[512 + tid]);
  float2 tw1 = make_float2(gtab[x1], gtab[512 + x1]);
  float2 tw2 = make_float2(gtab[x2], gtab[512 + x2]);
  float2 tw3 = make_float2(gtab[x3], gtab[512 + x3]);

  for (int k = tid; k < 513; k += 256) {
    float2 e = *(const float2*)&envp[k * NFR + fA];   // fA even -> 8B aligned
    hA[k] = e;                                        // (log ampA, log ampB)
  }
  __syncthreads();

  // ---- (1) packed cepstrum: z = envA_sym + i*envB_sym (both real even) ----
#pragma unroll
  for (int j = 0; j < 4; ++j) {
    int i = tid + 256 * j;
    int k = (i <= 512) ? i : 1024 - i;
    F[swz(i)] = hA[k];
  }
  fft_dif<+1>(F, tid, tw0, tw1, tw2, tw3);   // output in dr order
  // cep fold at k=dr4(p): scales 2^-10 / 2^-9 exact; upper half -> 0
#pragma unroll
  for (int j = 0; j < 4; ++j) {
    int p = tid + 256 * j;
    int k = dr4(p);
    float sc = ((k & 511) == 0) ? (1.0f / 1024.0f)
                                : ((k < 512) ? (2.0f / 1024.0f) : 0.0f);
    int e = swz(p);
    float2 a = F[e];
    F[e] = make_float2(a.x * sc, a.y * sc);
  }
  // ---- (2) packed rfft of two real cepstra; hermitian unpack; H=exp ----
  fft_dit<-1>(F, tid, tw0, tw1, tw2, tw3);   // dr input -> natural output
  for (int k = tid; k < 513; k += 256) {
    int k2 = (1024 - k) & 1023;
    float2 z = F[swz(k)], mm = F[swz(k2)];
    float GAr = 0.5f * (z.x + mm.x), GAi = 0.5f * (z.y - mm.y);
    float GBr = 0.5f * (z.y + mm.y), GBi = 0.5f * (mm.x - z.x);
    float er = expf(GAr);
    float si, co;
    sincosf(GAi, &si, &co);
    hA[k] = make_float2(er * co, er * si);
    er = expf(GBr);
    sincosf(GBi, &si, &co);
    hB[k] = make_float2(er * co, er * si);
  }
  __syncthreads();   // F reads above must finish before (3) overwrites F

  // hann weights: named scalars, loaded where first needed (L2-resident)
  float w0 = whg[tid], w1 = whg[tid + 256], w2 = whg[tid + 512], w3 = whg[tid + 768];

  // ---- (3) frame A: pack z = noise + i*pulse (windowed, reflect-padded) ----
#define PACK_FRAME(QOFF, WV, J)                                        \
  {                                                                    \
    int i = tid + 256 * (J);                                           \
    int q = (QOFF) + i;                                                \
    if (q < 0) q = -q;                                                 \
    else if (q >= L_TOT) q = 2 * L_TOT - 2 - q;                        \
    F[swz(i)] = make_float2(noise[q] * (WV), pulse[q] * (WV));         \
  }
  PACK_FRAME(256 * fA - 256, w0, 0)
  PACK_FRAME(256 * fA - 256, w1, 1)
  PACK_FRAME(256 * fA - 256, w2, 2)
  PACK_FRAME(256 * fA - 256, w3, 3)
  fft_dif<-1>(F, tid, tw0, tw1, tw2, tw3);   // dr-order spectrum
  float2 eA0 = *(const float2*)&envn[tid * NFR + fA];
  combine_one(tid, expf(eA0.x), F, hA);
  float2 eA1 = *(const float2*)&envn[(tid + 256) * NFR + fA];
  combine_one(tid + 256, expf(eA1.x), F, hA);
  float2 eA2 = make_float2(0.0f, 0.0f);
  if (tid == 0) {
    eA2 = *(const float2*)&envn[512 * NFR + fA];
    combine_one(512, expf(eA2.x), F, hA);
  }
  __syncthreads();   // F gathers above must finish before (4) overwrites F

  // ---- (4) frame B ----
  PACK_FRAME(256 * fA, w0, 0)
  PACK_FRAME(256 * fA, w1, 1)
  PACK_FRAME(256 * fA, w2, 2)
  PACK_FRAME(256 * fA, w3, 3)
  fft_dif<-1>(F, tid, tw0, tw1, tw2, tw3);
  combine_one(tid, expf(eA0.y), F, hB);
  combine_one(tid + 256, expf(eA1.y), F, hB);
  if (tid == 0) combine_one(512, expf(eA2.y), F, hB);
  __syncthreads();   // hA/hB visibility + F gathers done before (5) writes

  // ---- (5) packed hermitian inverse: Z = YA_full + i*YB_full, at dr positions ----
#pragma unroll
  for (int j = 0; j < 4; ++j) {
    int i = tid + 256 * j;
    float2 zv;
    if (i <= 512) {
      zv = make_float2(hA[i].x - hB[i].y, hA[i].y + hB[i].x);
    } else {
      int jj = 1024 - i;
      zv = make_float2(hA[jj].x + hB[jj].y, hB[jj].x - hA[jj].y);
    }
    F[swz(dr4(i))] = zv;
  }
  fft_dit<+1>(F, tid, tw0, tw1, tw2, tw3);   // natural-order time signal
  // fused OLA over the combined 1280-sample span: ya(i) + yb(i-256)
  const float scl = 1.0f / 1536.0f;          // 1/1024 FFT scale * 1/1.5 wsq
  {
    int tb = 256 * fA - 512 + tid;
    float val;
    // j=0
    val = F[swz(tid)].x * (w0 * scl);
    if (tb >= 0) atomicAdd(&out[tb], val);
    // j=1
    val = F[swz(tid + 256)].x * (w1 * scl) + F[swz(tid)].y * (w0 * scl);
    if (tb + 256 >= 0 && tb + 256 < OUTN) atomicAdd(&out[tb + 256], val);
    // j=2
    val = F[swz(tid + 512)].x * (w2 * scl) + F[swz(tid + 256)].y * (w1 * scl);
    if (tb + 512 < OUTN) atomicAdd(&out[tb + 512], val);
    // j=3
    val = F[swz(tid + 768)].x * (w3 * scl) + F[swz(tid + 512)].y * (w2 * scl);
    if (tb + 768 < OUTN) atomicAdd(&out[tb + 768], val);
    // j=4
    val = F[swz(tid + 768)].y * (w3 * scl);
    if (tb + 1024 < OUTN) atomicAdd(&out[tb + 1024], val);
  }
#undef PACK_FRAME
}

// ---------- edge fix-up: first/last 256 samples have <4 window terms ----------
__global__ __launch_bounds__(256) void finalize_kernel(float* __restrict__ out,
                                                       const float* __restrict__ W) {
  const float* wh = W + 2 * L_TOT + 1024;
  int tid = threadIdx.x;
  int t = (blockIdx.x == 0) ? tid : (OUTN - 256 + tid);
  int p = t + 512;
  int jmin = max(0, (p - 768) >> 8);
  int jmax = min(NFR - 1, p >> 8);
  float wsq = 0.0f;
  for (int j = jmin; j <= jmax; ++j) {
    float w = wh[p - 256 * j];
    wsq += w * w;
  }
  out[t] = out[t] * (1.5f / fmaxf(wsq, 1e-11f));
}

extern "C" void kernel_launch(void* const* d_in, const int* in_sizes, int n_in,
                              void* d_out, int out_size, void* d_ws, size_t ws_size,
                              hipStream_t stream) {
  const float* logf0 = (const float*)d_in[0];
  const float* envn  = (const float*)d_in[1];
  const float* envp  = (const float*)d_in[2];
  const float* noise = (const float*)d_in[3];
  float* out = (float*)d_out;
  float* W = (float*)d_ws;

  init_tables<<<dim3(72), dim3(256), 0, stream>>>(logf0, W);
  tree_kernel<<<dim3(2048), dim3(256), 0, stream>>>(W);
  tree_top_kernel<<<dim3(1), dim3(256), 0, stream>>>(W);
  pulse_kernel<<<dim3(L_TOT / 4096), dim3(256), 0, stream>>>(W);
  hipMemsetAsync(d_out, 0, (size_t)out_size * sizeof(float), stream);
  column_kernel<<<dim3(NFR / 2), dim3(256), 0, stream>>>(noise, envn, envp, W, out);
  finalize_kernel<<<dim3(2), dim3(256), 0, stream>>>(out, W);
}

// Round 4
// 238.569 us; speedup vs baseline: 2.8327x; 1.1639x over previous
//
#include <hip/hip_runtime.h>
#include <math.h>

#define L_TOT 4194304   // 2^22 upsampled samples
#define NFR   16384     // frames / f0 length
#define OUTN  4194048   // output length

// ---------- workspace layout (floats) ----------
// [0, L_TOT)                : cumsum tree levels 11..22 (packed; lower levels in LDS)
// [L_TOT, 2*L_TOT)          : pulse signal
// [2*L_TOT + 0,   +512)     : twiddle cos  (cos(2*pi*j/1024))
// [2*L_TOT + 512, +1024)    : twiddle sin
// [2*L_TOT + 1024,+2048)    : hann window (1024)
// [2*L_TOT + 2048,+2048+NFR): f0 = exp(log_f0)

__device__ __forceinline__ int lvl_off(int a) {
  return L_TOT - (L_TOT >> (a - 1));
}

// LDS bank swizzle for the 1024-entry float2 in-place FFT buffer.
// Folds ALL upper address bits into the low nibble so that every access
// pattern in this kernel (FFT strides 256/64/16/4/1, natural loops, and the
// digit-reversed gathers with entropy in bits 8/6) is conflict-free.
__device__ __forceinline__ int swz(int e) {
  int h = (e >> 4) & 3, g = (e >> 6) & 3, f = (e >> 8) & 3;
  return e ^ (h * 5) ^ (g * 3) ^ ((f * 12) & 15);
}

// base-4 digit reversal of a 10-bit index (involution).
__device__ __forceinline__ int dr4(int p) {
  return ((p & 3) << 8) | (((p >> 2) & 3) << 6) | (((p >> 4) & 3) << 4) |
         (((p >> 6) & 3) << 2) | ((p >> 8) & 3);
}

// linear_interp(exp(log_f0), 256) at position j — matches reference rounding (no FMA)
__device__ __forceinline__ float f0_up_val(const float* f0arr, int j) {
  float pos = __fadd_rn(__fmul_rn(__fadd_rn((float)j, 0.5f), 1.0f / 256.0f), -0.5f);
  pos = fminf(fmaxf(pos, 0.0f), 16383.0f);
  int lo = (int)pos;
  int hi = min(lo + 1, NFR - 1);
  float frac = __fadd_rn(pos, -(float)lo);
  float a = __fmul_rn(f0arr[lo], __fadd_rn(1.0f, -frac));
  float b = __fmul_rn(f0arr[hi], frac);
  return __fadd_rn(a, b);
}

// full prefix sum replicating jax.lax.associative_scan bit-exactly (validated R4-R8).
__device__ float prefix_sum(const float* W, const float* f0arr, int m) {
  float acc = 0.0f;
  bool first = true;
  int pos = 0;
  for (int a = 22; a >= 1; --a) {
    if (m & (1 << a)) {
      float node = W[lvl_off(a) + (pos >> a)];
      acc = first ? node : __fadd_rn(acc, node);
      first = false;
      pos += (1 << a);
    }
  }
  if (m & 1) {
    float node = f0_up_val(f0arr, pos);
    acc = first ? node : __fadd_rn(acc, node);
  }
  return acc;
}

// ---------- init: twiddles, window, f0 ----------
__global__ __launch_bounds__(256) void init_tables(const float* __restrict__ logf0,
                                                   float* __restrict__ W) {
  int g = blockIdx.x * 256 + threadIdx.x;
  float* twc = W + 2 * L_TOT;
  float* tws = twc + 512;
  float* wh  = twc + 1024;
  float* f0arr = twc + 2048;
  if (g < 512) {
    double a = (double)g * 3.14159265358979323846 / 512.0; // 2*pi*g/1024
    twc[g] = (float)cos(a);
    tws[g] = (float)sin(a);
  }
  if (g < 1024) {
    double a = (double)g * 3.14159265358979323846 / 512.0;
    wh[g] = (float)(0.5 - 0.5 * cos(a));
  }
  if (g >= 2048 && g < 2048 + NFR) {
    f0arr[g - 2048] = (float)exp((double)logf0[g - 2048]);
  }
}

// ---------- cumsum tree: build levels 1..11, store only level 11 ----------
__global__ __launch_bounds__(256) void tree_kernel(float* W) {
  const float* f0arr = W + 2 * L_TOT + 2048;
  __shared__ float A[2048];
  __shared__ float B[1024];
  int tid = threadIdx.x;
  int base = blockIdx.x * 2048;
  for (int i = tid; i < 2048; i += 256) A[i] = f0_up_val(f0arr, base + i);
  __syncthreads();
  float* src = A;
  float* dst = B;
  int cnt = 1024;
  for (int a = 1; a <= 11; ++a) {
    int gbase = base >> a;
    for (int i = tid; i < cnt; i += 256) {
      float v = __fadd_rn(src[2 * i], src[2 * i + 1]);
      dst[i] = v;
      if (a == 11) W[lvl_off(11) + gbase + i] = v;
    }
    __syncthreads();
    float* tmp = src; src = dst; dst = tmp;
    cnt >>= 1;
  }
}

// ---------- cumsum tree, levels 12..22 ----------
__global__ __launch_bounds__(256) void tree_top_kernel(float* W) {
  __shared__ float A[2048];
  __shared__ float B[1024];
  int tid = threadIdx.x;
  for (int i = tid; i < 2048; i += 256) A[i] = W[lvl_off(11) + i];
  __syncthreads();
  float* src = A;
  float* dst = B;
  int cnt = 1024;
  for (int a = 12; a <= 22; ++a) {
    for (int i = tid; i < cnt; i += 256) {
      float v = __fadd_rn(src[2 * i], src[2 * i + 1]);
      dst[i] = v;
      W[lvl_off(a) + i] = v;
    }
    __syncthreads();
    float* tmp = src; src = dst; dst = tmp;
    cnt >>= 1;
  }
}

// ---------- impulse train v3 (bit-exact, validated R4-R8) ----------
__global__ __launch_bounds__(256) void pulse_kernel(float* W) {
  const float* f0arr = W + 2 * L_TOT + 2048;
  __shared__ float Tl[510];
  __shared__ float P[4100];
  int tid = threadIdx.x;
  int base = blockIdx.x * 4096;

  float v[16];
#pragma unroll
  for (int c = 0; c < 16; ++c) v[c] = f0_up_val(f0arr, base + 16 * tid + c);
  float s2[8], s4[4], s8[2];
#pragma unroll
  for (int j = 0; j < 8; ++j) s2[j] = __fadd_rn(v[2 * j], v[2 * j + 1]);
#pragma unroll
  for (int j = 0; j < 4; ++j) s4[j] = __fadd_rn(s2[2 * j], s2[2 * j + 1]);
  s8[0] = __fadd_rn(s4[0], s4[1]);
  s8[1] = __fadd_rn(s4[2], s4[3]);
  Tl[tid] = __fadd_rn(s8[0], s8[1]);
  __syncthreads();
  if (tid < 128) Tl[256 + tid] = __fadd_rn(Tl[2 * tid], Tl[2 * tid + 1]);
  __syncthreads();
  if (tid < 64)  Tl[384 + tid] = __fadd_rn(Tl[256 + 2 * tid], Tl[256 + 2 * tid + 1]);
  __syncthreads();
  if (tid < 32)  Tl[448 + tid] = __fadd_rn(Tl[384 + 2 * tid], Tl[384 + 2 * tid + 1]);
  __syncthreads();
  if (tid < 16)  Tl[480 + tid] = __fadd_rn(Tl[448 + 2 * tid], Tl[448 + 2 * tid + 1]);
  __syncthreads();
  if (tid < 8)   Tl[496 + tid] = __fadd_rn(Tl[480 + 2 * tid], Tl[480 + 2 * tid + 1]);
  __syncthreads();
  if (tid < 4)   Tl[504 + tid] = __fadd_rn(Tl[496 + 2 * tid], Tl[496 + 2 * tid + 1]);
  __syncthreads();
  if (tid < 2)   Tl[508 + tid] = __fadd_rn(Tl[504 + 2 * tid], Tl[504 + 2 * tid + 1]);
  __syncthreads();

  float accT = 0.0f;
  bool firstT = true;
  {
    int pos = 0;
    for (int a = 22; a >= 12; --a) {
      if (base & (1 << a)) {
        float node = W[lvl_off(a) + (pos >> a)];
        accT = firstT ? node : __fadd_rn(accT, node);
        firstT = false;
        pos += (1 << a);
      }
    }
  }
  float accM = accT;
  bool firstM = firstT;
  {
    int rh = 16 * tid;
    int lpos = 0;
    for (int a = 11; a >= 4; --a) {
      if (rh & (1 << a)) {
        float node = Tl[512 - (512 >> (a - 4)) + (lpos >> a)];
        accM = firstM ? node : __fadd_rn(accM, node);
        firstM = false;
        lpos += (1 << a);
      }
    }
  }
  if (tid >= 1) P[16 * tid] = accM;
#pragma unroll
  for (int c = 1; c <= 15; ++c) {
    float acc = accM;
    bool first = firstM;
    int lp = 0;
    if (c & 8) { float n = s8[lp >> 3]; acc = first ? n : __fadd_rn(acc, n); first = false; lp += 8; }
    if (c & 4) { float n = s4[lp >> 2]; acc = first ? n : __fadd_rn(acc, n); first = false; lp += 4; }
    if (c & 2) { float n = s2[lp >> 1]; acc = first ? n : __fadd_rn(acc, n); first = false; lp += 2; }
    if (c & 1) { float n = v[lp];       acc = first ? n : __fadd_rn(acc, n); }
    P[16 * tid + c] = acc;
  }
  if (tid == 0) P[4096] = prefix_sum(W, f0arr, base + 4096);
  if (tid == 1) {
    int m2 = base + 4097;
    P[4097] = (m2 <= L_TOT) ? prefix_sum(W, f0arr, m2) : 0.0f;
  }
  __syncthreads();

  float o[16];
#pragma unroll
  for (int c = 0; c < 16; ++c) {
    int i = base + 16 * tid + c;
    float P1 = P[16 * tid + c + 1];
    float P2 = (i == L_TOT - 1) ? prefix_sum(W, f0arr, 1)
                                : P[16 * tid + c + 2];
    float t1 = __fdiv_rn(P1, 24000.0f);
    float saw1 = __fadd_rn(t1, -floorf(t1));
    float t2 = __fdiv_rn(P2, 24000.0f);
    float saw2 = __fadd_rn(t2, -floorf(t2));
    float cc = __fdiv_rn(v[c], 24000.0f);
    o[c] = __fadd_rn(__fadd_rn(saw1, -saw2), cc);
  }
#pragma unroll
  for (int k = 0; k < 4; ++k)
    *(float4*)&W[L_TOT + base + 16 * tid + 4 * k] =
        make_float4(o[4 * k], o[4 * k + 1], o[4 * k + 2], o[4 * k + 3]);
}

// ---------- in-place radix-4 FFT, N=1024, 256 threads ----------
// DIF: natural -> base-4 digit-reversed.  DIT: digit-reversed -> natural.
// Twiddles live in small LDS tables read per stage (R3 lesson: keeping them
// in registers for the whole kernel cost 12 VGPRs -> occupancy 8->6 waves/SIMD;
// R2 lesson: indexed per-thread arrays go to scratch). Table reads are
// consecutive-lane or same-address broadcast -> conflict-free.
//   T0[t]=w^t (257), T1[t]=w^{4t} (64), T2[t]=w^{16t} (16), T3[t]=w^{64t} (4)
// w = e^{+2pi i/1024}; DIR<0 conjugates. Each thread RMWs its own 4 elements.

template <int DIR>
__device__ __forceinline__ void bfly_dif(float2* F, int base, int L, float ur, float ui) {
  if (DIR < 0) ui = -ui;
  int e0 = swz(base), e1 = swz(base + L), e2 = swz(base + 2 * L), e3 = swz(base + 3 * L);
  float2 x0 = F[e0], x1 = F[e1], x2 = F[e2], x3 = F[e3];
  float s0r = x0.x + x2.x, s0i = x0.y + x2.y;
  float s1r = x1.x + x3.x, s1i = x1.y + x3.y;
  float d0r = x0.x - x2.x, d0i = x0.y - x2.y;
  float ddr = x1.x - x3.x, ddi = x1.y - x3.y;
  float t3r = (DIR > 0) ? -ddi : ddi;      // DIR*i*(x1-x3)
  float t3i = (DIR > 0) ? ddr : -ddr;
  float vr = ur * ur - ui * ui, vi = 2.0f * ur * ui;      // w^{2q'}
  float w3r = ur * vr - ui * vi, w3i = ur * vi + ui * vr; // w^{3q'}
  F[e0] = make_float2(s0r + s1r, s0i + s1i);
  float a1r = d0r + t3r, a1i = d0i + t3i;
  F[e1] = make_float2(a1r * ur - a1i * ui, a1r * ui + a1i * ur);
  float a2r = s0r - s1r, a2i = s0i - s1i;
  F[e2] = make_float2(a2r * vr - a2i * vi, a2r * vi + a2i * vr);
  float a3r = d0r - t3r, a3i = d0i - t3i;
  F[e3] = make_float2(a3r * w3r - a3i * w3i, a3r * w3i + a3i * w3r);
  __syncthreads();
}

template <int DIR>
__device__ __forceinline__ void bfly_dit(float2* F, int base, int L, float ur, float ui) {
  if (DIR < 0) ui = -ui;
  int e0 = swz(base), e1 = swz(base + L), e2 = swz(base + 2 * L), e3 = swz(base + 3 * L);
  float2 x0 = F[e0], x1 = F[e1], x2 = F[e2], x3 = F[e3];
  float vr = ur * ur - ui * ui, vi = 2.0f * ur * ui;
  float w3r = ur * vr - ui * vi, w3i = ur * vi + ui * vr;
  float b1r = x1.x * ur - x1.y * ui, b1i = x1.x * ui + x1.y * ur;
  float b2r = x2.x * vr - x2.y * vi, b2i = x2.x * vi + x2.y * vr;
  float b3r = x3.x * w3r - x3.y * w3i, b3i = x3.x * w3i + x3.y * w3r;
  float s0r = x0.x + b2r, s0i = x0.y + b2i;
  float d0r = x0.x - b2r, d0i = x0.y - b2i;
  float s1r = b1r + b3r, s1i = b1i + b3i;
  float ddr = b1r - b3r, ddi = b1i - b3i;
  float d1r = (DIR > 0) ? -ddi : ddi;      // DIR*i*(t1-t3)
  float d1i = (DIR > 0) ? ddr : -ddr;
  F[e0] = make_float2(s0r + s1r, s0i + s1i);
  F[e1] = make_float2(d0r + d1r, d0i + d1i);
  F[e2] = make_float2(s0r - s1r, s0i - s1i);
  F[e3] = make_float2(d0r - d1r, d0i - d1i);
  __syncthreads();
}

template <int DIR>
__device__ __forceinline__ void fft_dif(float2* F, int tid, const float2* T0,
                                        const float2* T1, const float2* T2,
                                        const float2* T3) {
  __syncthreads();
  float2 t;
  t = T0[tid];      bfly_dif<DIR>(F, tid, 256, t.x, t.y);
  t = T1[tid & 63]; bfly_dif<DIR>(F, ((tid >> 6) << 8) | (tid & 63), 64, t.x, t.y);
  t = T2[tid & 15]; bfly_dif<DIR>(F, ((tid >> 4) << 6) | (tid & 15), 16, t.x, t.y);
  t = T3[tid & 3];  bfly_dif<DIR>(F, ((tid >> 2) << 4) | (tid & 3), 4, t.x, t.y);
  bfly_dif<DIR>(F, tid << 2, 1, 1.0f, 0.0f);
}

template <int DIR>
__device__ __forceinline__ void fft_dit(float2* F, int tid, const float2* T0,
                                        const float2* T1, const float2* T2,
                                        const float2* T3) {
  __syncthreads();
  float2 t;
  bfly_dit<DIR>(F, tid << 2, 1, 1.0f, 0.0f);
  t = T3[tid & 3];  bfly_dit<DIR>(F, ((tid >> 2) << 4) | (tid & 3), 4, t.x, t.y);
  t = T2[tid & 15]; bfly_dit<DIR>(F, ((tid >> 4) << 6) | (tid & 15), 16, t.x, t.y);
  t = T1[tid & 63]; bfly_dit<DIR>(F, ((tid >> 6) << 8) | (tid & 63), 64, t.x, t.y);
  t = T0[tid];      bfly_dit<DIR>(F, tid, 256, t.x, t.y);
}

// Hann from quarter table: w(i) = 0.5 - 0.5*cos(2*pi*i/1024)
// mirror: i>512 -> 1024-i; j in (256,512] -> cos = -T0[512-j].x; T0[256].x == 0.
__device__ __forceinline__ float hann_w(int i, const float2* T0) {
  int j = (i > 512) ? (1024 - i) : i;
  float c = (j <= 256) ? T0[j].x : -T0[512 - j].x;
  return 0.5f - 0.5f * c;
}

// spectral combine for one bin k (F holds a DIF output, i.e. dr order):
// H[k] <- Sp[k]*H[k] + Sn[k]*An
__device__ __forceinline__ void combine_one(int k, float An, const float2* F, float2* H) {
  int k2 = (1024 - k) & 1023;
  float2 z = F[swz(dr4(k))], mm = F[swz(dr4(k2))];
  float Ar = 0.5f * (z.x + mm.x), Ai = 0.5f * (z.y - mm.y);  // even (noise) part
  float Br = 0.5f * (z.y + mm.y), Bi = 0.5f * (mm.x - z.x);  // odd (pulse) part
  float2 h = H[k];
  H[k] = make_float2(Br * h.x - Bi * h.y + Ar * An,
                     Br * h.y + Bi * h.x + Ai * An);
}

// ---------- per-block fused kernel: TWO adjacent frames, 5 in-place FFTs ----------
// LDS = F[1024] + hA/hB[513] + TW[341] = 19128 B -> 8 blocks/CU (wave cap).
// All twiddle/window state lives in LDS -> VGPR stays <= 64 (8 waves/SIMD).
__global__ __launch_bounds__(256) void column_kernel(
    const float* __restrict__ noise,
    const float* __restrict__ envn,
    const float* __restrict__ envp,
    const float* __restrict__ W,
    float* __restrict__ out) {
  __shared__ float2 F[1024];             // single in-place FFT buffer
  __shared__ float2 hA[513], hB[513];
  __shared__ float2 TW[341];             // [0,257): w^t; [257,321): w^4t; [321,337): w^16t; [337,341): w^64t
  int tid = threadIdx.x;
  int bid = blockIdx.x;
  // XCD swizzle: each XCD streams a contiguous frame range (env L2 locality).
  int g = (bid & 7) * 1024 + (bid >> 3);
  int fA = 2 * g;                        // frames fA, fA+1
  const float* pulse = W + L_TOT;
  const float* gtab = W + 2 * L_TOT;
  const float2* T0 = TW;
  const float2* T1 = TW + 257;
  const float2* T2 = TW + 321;
  const float2* T3 = TW + 337;

  for (int i = tid; i < 341; i += 256) {
    int e;
    if (i < 257) e = i;
    else if (i < 321) e = (i - 257) << 2;
    else if (i < 337) e = (i - 321) << 4;
    else e = (i - 337) << 6;
    TW[i] = make_float2(gtab[e], gtab[512 + e]);
  }
  for (int k = tid; k < 513; k += 256) {
    float2 e = *(const float2*)&envp[k * NFR + fA];   // fA even -> 8B aligned
    hA[k] = e;                                        // (log ampA, log ampB)
  }
  __syncthreads();

  // ---- (1) packed cepstrum: z = envA_sym + i*envB_sym (both real even) ----
#pragma unroll
  for (int j = 0; j < 4; ++j) {
    int i = tid + 256 * j;
    int k = (i <= 512) ? i : 1024 - i;
    F[swz(i)] = hA[k];
  }
  fft_dif<+1>(F, tid, T0, T1, T2, T3);   // output in dr order
  // cep fold at k=dr4(p): scales 2^-10 / 2^-9 exact; upper half -> 0
#pragma unroll
  for (int j = 0; j < 4; ++j) {
    int p = tid + 256 * j;
    int k = dr4(p);
    float sc = ((k & 511) == 0) ? (1.0f / 1024.0f)
                                : ((k < 512) ? (2.0f / 1024.0f) : 0.0f);
    int e = swz(p);
    float2 a = F[e];
    F[e] = make_float2(a.x * sc, a.y * sc);
  }
  // ---- (2) packed rfft of two real cepstra; hermitian unpack; H=exp ----
  fft_dit<-1>(F, tid, T0, T1, T2, T3);   // dr input -> natural output
  for (int k = tid; k < 513; k += 256) {
    int k2 = (1024 - k) & 1023;
    float2 z = F[swz(k)], mm = F[swz(k2)];
    float GAr = 0.5f * (z.x + mm.x), GAi = 0.5f * (z.y - mm.y);
    float GBr = 0.5f * (z.y + mm.y), GBi = 0.5f * (mm.x - z.x);
    float er = expf(GAr);
    float si, co;
    sincosf(GAi, &si, &co);
    hA[k] = make_float2(er * co, er * si);
    er = expf(GBr);
    sincosf(GBi, &si, &co);
    hB[k] = make_float2(er * co, er * si);
  }
  __syncthreads();   // F reads above must finish before (3) overwrites F

  // ---- (3) frame A: pack z = noise + i*pulse (windowed, reflect-padded) ----
#define PACK_FRAME(QOFF, J)                                            \
  {                                                                    \
    int i = tid + 256 * (J);                                           \
    int q = (QOFF) + i;                                                \
    if (q < 0) q = -q;                                                 \
    else if (q >= L_TOT) q = 2 * L_TOT - 2 - q;                        \
    float wv = hann_w(i, T0);                                          \
    F[swz(i)] = make_float2(noise[q] * wv, pulse[q] * wv);             \
  }
  PACK_FRAME(256 * fA - 256, 0)
  PACK_FRAME(256 * fA - 256, 1)
  PACK_FRAME(256 * fA - 256, 2)
  PACK_FRAME(256 * fA - 256, 3)
  fft_dif<-1>(F, tid, T0, T1, T2, T3);   // dr-order spectrum
  float2 eA0 = *(const float2*)&envn[tid * NFR + fA];
  combine_one(tid, expf(eA0.x), F, hA);
  float2 eA1 = *(const float2*)&envn[(tid + 256) * NFR + fA];
  combine_one(tid + 256, expf(eA1.x), F, hA);
  float2 eA2 = make_float2(0.0f, 0.0f);
  if (tid == 0) {
    eA2 = *(const float2*)&envn[512 * NFR + fA];
    combine_one(512, expf(eA2.x), F, hA);
  }
  __syncthreads();   // F gathers above must finish before (4) overwrites F

  // ---- (4) frame B ----
  PACK_FRAME(256 * fA, 0)
  PACK_FRAME(256 * fA, 1)
  PACK_FRAME(256 * fA, 2)
  PACK_FRAME(256 * fA, 3)
  fft_dif<-1>(F, tid, T0, T1, T2, T3);
  combine_one(tid, expf(eA0.y), F, hB);
  combine_one(tid + 256, expf(eA1.y), F, hB);
  if (tid == 0) combine_one(512, expf(eA2.y), F, hB);
  __syncthreads();   // hA/hB visibility + F gathers done before (5) writes

  // ---- (5) packed hermitian inverse: Z = YA_full + i*YB_full, at dr positions ----
#pragma unroll
  for (int j = 0; j < 4; ++j) {
    int i = tid + 256 * j;
    float2 zv;
    if (i <= 512) {
      zv = make_float2(hA[i].x - hB[i].y, hA[i].y + hB[i].x);
    } else {
      int jj = 1024 - i;
      zv = make_float2(hA[jj].x + hB[jj].y, hB[jj].x - hA[jj].y);
    }
    F[swz(dr4(i))] = zv;
  }
  fft_dit<+1>(F, tid, T0, T1, T2, T3);   // natural-order time signal
  // fused OLA over the combined 1280-sample span: ya(i) + yb(i-256)
  const float scl = 1.0f / 1536.0f;      // 1/1024 FFT scale * 1/1.5 wsq
  {
    float2 f0v = F[swz(tid)];
    float2 f1v = F[swz(tid + 256)];
    float2 f2v = F[swz(tid + 512)];
    float2 f3v = F[swz(tid + 768)];
    float hw0 = hann_w(tid, T0) * scl;
    float hw1 = hann_w(tid + 256, T0) * scl;
    float hw2 = hann_w(tid + 512, T0) * scl;
    float hw3 = hann_w(tid + 768, T0) * scl;
    int tb = 256 * fA - 512 + tid;
    float val;
    // j=0
    val = f0v.x * hw0;
    if (tb >= 0) atomicAdd(&out[tb], val);
    // j=1
    val = f1v.x * hw1 + f0v.y * hw0;
    if (tb + 256 >= 0 && tb + 256 < OUTN) atomicAdd(&out[tb + 256], val);
    // j=2
    val = f2v.x * hw2 + f1v.y * hw1;
    if (tb + 512 < OUTN) atomicAdd(&out[tb + 512], val);
    // j=3
    val = f3v.x * hw3 + f2v.y * hw2;
    if (tb + 768 < OUTN) atomicAdd(&out[tb + 768], val);
    // j=4
    val = f3v.y * hw3;
    if (tb + 1024 < OUTN) atomicAdd(&out[tb + 1024], val);
  }
#undef PACK_FRAME
}

// ---------- edge fix-up: first/last 256 samples have <4 window terms ----------
__global__ __launch_bounds__(256) void finalize_kernel(float* __restrict__ out,
                                                       const float* __restrict__ W) {
  const float* wh = W + 2 * L_TOT + 1024;
  int tid = threadIdx.x;
  int t = (blockIdx.x == 0) ? tid : (OUTN - 256 + tid);
  int p = t + 512;
  int jmin = max(0, (p - 768) >> 8);
  int jmax = min(NFR - 1, p >> 8);
  float wsq = 0.0f;
  for (int j = jmin; j <= jmax; ++j) {
    float w = wh[p - 256 * j];
    wsq += w * w;
  }
  out[t] = out[t] * (1.5f / fmaxf(wsq, 1e-11f));
}

extern "C" void kernel_launch(void* const* d_in, const int* in_sizes, int n_in,
                              void* d_out, int out_size, void* d_ws, size_t ws_size,
                              hipStream_t stream) {
  const float* logf0 = (const float*)d_in[0];
  const float* envn  = (const float*)d_in[1];
  const float* envp  = (const float*)d_in[2];
  const float* noise = (const float*)d_in[3];
  float* out = (float*)d_out;
  float* W = (float*)d_ws;

  init_tables<<<dim3(72), dim3(256), 0, stream>>>(logf0, W);
  tree_kernel<<<dim3(2048), dim3(256), 0, stream>>>(W);
  tree_top_kernel<<<dim3(1), dim3(256), 0, stream>>>(W);
  pulse_kernel<<<dim3(L_TOT / 4096), dim3(256), 0, stream>>>(W);
  hipMemsetAsync(d_out, 0, (size_t)out_size * sizeof(float), stream);
  column_kernel<<<dim3(NFR / 2), dim3(256), 0, stream>>>(noise, envn, envp, W, out);
  finalize_kernel<<<dim3(2), dim3(256), 0, stream>>>(out, W);
}